// Round 2
// baseline (1020.299 us; speedup 1.0000x reference)
//
#include <hip/hip_runtime.h>
#include <hip/hip_bf16.h>

// Problem constants (B,N,D,H,E from reference; hd = D/H)
#define BB   2
#define NN   2048
#define DD   256
#define HH   8
#define HD   32
#define EE   65536
#define KTOP 1024   // N * (1 - 0.5)
#define NT   13     // float tensors to canonicalize

__device__ __forceinline__ float bf2f(unsigned short u) {
    return __uint_as_float(((unsigned)u) << 16);
}
__device__ __forceinline__ unsigned short f2bf(float f) {
    __hip_bfloat16 h = __float2bfloat16(f);
    return *reinterpret_cast<unsigned short*>(&h);
}

// ---------------------------------------------------------------------------
// Dtype detector: read first 64K ushorts of x as bf16. fp32 data misread as
// bf16 has random exponents in the odd halves -> max blows past 1e10.
// Genuine bf16 N(0,1) data -> max ~5. flag: 1 = fp32, 0 = bf16.
// ---------------------------------------------------------------------------
__global__ __launch_bounds__(256) void k_detect(const void* __restrict__ x, int* __restrict__ flag)
{
    __shared__ float red[256];
    const unsigned short* u = (const unsigned short*)x;
    float mx = 0.f;
    for (int i = threadIdx.x; i < 65536; i += 256) {
        float v = fabsf(bf2f(u[i]));
        if (!(v <= 1e10f)) v = 1e30f;       // NaN / inf / huge -> big
        mx = fmaxf(mx, v);
    }
    red[threadIdx.x] = mx;
    __syncthreads();
    for (int s = 128; s > 0; s >>= 1) {
        if (threadIdx.x < s) red[threadIdx.x] = fmaxf(red[threadIdx.x], red[threadIdx.x + s]);
        __syncthreads();
    }
    if (threadIdx.x == 0) *flag = (red[0] > 1e10f) ? 1 : 0;
}

// ---------------------------------------------------------------------------
// Canonicalize all float tensors to fp32 in workspace.
// ---------------------------------------------------------------------------
struct ConvArgs {
    const void* src[NT];
    float*      dst[NT];
    int         n[NT];
};

__global__ __launch_bounds__(256) void k_convert(ConvArgs a, const int* __restrict__ flag)
{
    int t = blockIdx.y;
    int n = a.n[t];
    int fp = *flag;
    const float* sf = (const float*)a.src[t];
    const unsigned short* sb = (const unsigned short*)a.src[t];
    float* d = a.dst[t];
    for (int i = blockIdx.x * 256 + threadIdx.x; i < n; i += gridDim.x * 256)
        d[i] = fp ? sf[i] : bf2f(sb[i]);
}

// ---------------------------------------------------------------------------
// topo[b,n] = g2 @ relu(g1 @ x[b,n] + g1_b) + g2_b      (hidden = 128)
// grid: B*N blocks, 128 threads (one thread per hidden unit)
// ---------------------------------------------------------------------------
__global__ __launch_bounds__(128) void k_topo(
    const float* __restrict__ x,
    const float* __restrict__ g1w, const float* __restrict__ g1b,
    const float* __restrict__ g2w, const float* __restrict__ g2b,
    float* __restrict__ topo)
{
    int row = blockIdx.x;            // b*N + n
    int t   = threadIdx.x;           // 0..127 (hidden unit)
    __shared__ float xs[DD];
    __shared__ float red[128];
    for (int i = t; i < DD; i += 128) xs[i] = x[(size_t)row * DD + i];
    __syncthreads();
    float acc = 0.f;
    const float* wrow = g1w + (size_t)t * DD;
    for (int k = 0; k < DD; ++k) acc += xs[k] * wrow[k];
    acc += g1b[t];
    acc = fmaxf(acc, 0.f);
    acc *= g2w[t];
    red[t] = acc;
    __syncthreads();
    for (int s = 64; s > 0; s >>= 1) { if (t < s) red[t] += red[t + s]; __syncthreads(); }
    if (t == 0) topo[row] = red[0] + g2b[0];
}

// ---------------------------------------------------------------------------
// Stable top-k -> column bit mask. rank(m) = #{j: v[j]>v[m]} + #{j<m: v[j]==v[m]}
// selected iff rank < KTOP  (matches jax.lax.top_k stable-tie semantics).
// ---------------------------------------------------------------------------
__global__ __launch_bounds__(256) void k_rank(
    const float* __restrict__ topo, unsigned* __restrict__ colbits)
{
    int b = blockIdx.y;
    int m = blockIdx.x * 256 + threadIdx.x;
    __shared__ float tl[NN];
    for (int i = threadIdx.x; i < NN; i += 256) tl[i] = topo[b * NN + i];
    __syncthreads();
    float v = tl[m];
    int rank = 0;
    for (int j = 0; j < NN; ++j) {
        float vj = tl[j];
        rank += (vj > v) || (vj == v && j < m);
    }
    if (rank < KTOP) atomicOr(&colbits[b * 64 + (m >> 5)], 1u << (m & 31));
}

// ---------------------------------------------------------------------------
// Edge bitmask: edgebits[n][m/32] |= bit(m) for each edge (n=row, m=col)
// ---------------------------------------------------------------------------
__global__ __launch_bounds__(256) void k_edges(
    const int* __restrict__ ei, unsigned* __restrict__ edgebits)
{
    int e = blockIdx.x * 256 + threadIdx.x;
    if (e >= EE) return;
    int r = ei[e];
    int c = ei[EE + e];
    atomicOr(&edgebits[r * 64 + (c >> 5)], 1u << (c & 31));
}

// ---------------------------------------------------------------------------
// sparse_mask output [B,H,N,N]: value = edge|col bit. One block per (b,n)
// row; each thread emits 8 elements per head. Store dtype from flag.
// ---------------------------------------------------------------------------
__global__ __launch_bounds__(256) void k_maskout(
    const unsigned* __restrict__ edgebits, const unsigned* __restrict__ colbits,
    void* __restrict__ dout, const int* __restrict__ flag)
{
    int row = blockIdx.x;                 // b*N + n
    int b = row / NN, n = row % NN;
    int t = threadIdx.x;                  // covers cols t*8 .. t*8+7
    unsigned w = edgebits[n * 64 + (t >> 2)] | colbits[b * 64 + (t >> 2)];
    unsigned bits = (w >> ((t & 3) * 8)) & 0xFFu;
    if (*flag) {
        float v[8];
#pragma unroll
        for (int i = 0; i < 8; ++i) v[i] = ((bits >> i) & 1) ? 1.f : 0.f;
        float* base = (float*)dout + (size_t)BB * NN * DD;
#pragma unroll
        for (int h = 0; h < HH; ++h) {
            size_t idx = ((((size_t)(b * HH + h)) * NN + n) * NN) + (size_t)t * 8;
            *reinterpret_cast<float4*>(base + idx)     = make_float4(v[0], v[1], v[2], v[3]);
            *reinterpret_cast<float4*>(base + idx + 4) = make_float4(v[4], v[5], v[6], v[7]);
        }
    } else {
        unsigned v[8];
#pragma unroll
        for (int i = 0; i < 8; ++i) v[i] = ((bits >> i) & 1) ? 0x3F80u : 0u;
        uint4 o4;
        o4.x = v[0] | (v[1] << 16);
        o4.y = v[2] | (v[3] << 16);
        o4.z = v[4] | (v[5] << 16);
        o4.w = v[6] | (v[7] << 16);
        unsigned short* base = (unsigned short*)dout + (size_t)BB * NN * DD;
#pragma unroll
        for (int h = 0; h < HH; ++h) {
            size_t idx = ((((size_t)(b * HH + h)) * NN + n) * NN) + (size_t)t * 8;
            *reinterpret_cast<uint4*>(base + idx) = o4;
        }
    }
}

// ---------------------------------------------------------------------------
// GEMM: out[row, col] = X[row,:] . W[col,:] + bias[col]
// X:[4096,256] fp32, W:[256,256] fp32 row-major. 16 rows x 256 cols / block.
// mode 0: scatter fp32 to internal [b][h][n][j] head layout (outF).
// mode 1: store to d_out (dtype per flag), row-major [row][col].
// ---------------------------------------------------------------------------
__global__ __launch_bounds__(256) void k_gemm(
    const float* __restrict__ X, const float* __restrict__ W,
    const float* __restrict__ bias, float* __restrict__ outF,
    void* __restrict__ dout, const int* __restrict__ flag, int mode)
{
    __shared__ float xs[16][DD];
    __shared__ float wt[16][257];
    int t = threadIdx.x;
    int row0 = blockIdx.x * 16;
    {   // vectorized X tile load: 16 rows x 256 cols = 1024 float4
        const float4* X4 = reinterpret_cast<const float4*>(X + (size_t)row0 * DD);
        for (int i = t; i < 16 * 64; i += 256) {
            int r = i >> 6, k4 = i & 63;
            *reinterpret_cast<float4*>(&xs[r][k4 * 4]) = X4[(size_t)r * 64 + k4];
        }
    }
    float acc[16];
#pragma unroll
    for (int r = 0; r < 16; ++r) acc[r] = 0.f;

    for (int kt = 0; kt < DD; kt += 16) {
        __syncthreads();
        for (int i = t; i < 256 * 16; i += 256) {
            int nn = i >> 4, kk = i & 15;
            wt[kk][nn] = W[(size_t)nn * DD + kt + kk];
        }
        __syncthreads();
#pragma unroll
        for (int kk = 0; kk < 16; ++kk) {
            float wv = wt[kk][t];
#pragma unroll
            for (int r = 0; r < 16; ++r) acc[r] += xs[r][kt + kk] * wv;
        }
    }
    float bv = bias[t];
    if (mode == 0) {
        int hh = t >> 5, j = t & 31;
#pragma unroll
        for (int r = 0; r < 16; ++r) {
            int row = row0 + r;
            int b = row / NN, n2 = row % NN;
            outF[(((size_t)(b * HH + hh)) * NN + n2) * HD + j] = acc[r] + bv;
        }
    } else {
        if (*flag) {
            float* o = (float*)dout;
#pragma unroll
            for (int r = 0; r < 16; ++r) o[(size_t)(row0 + r) * DD + t] = acc[r] + bv;
        } else {
            unsigned short* o = (unsigned short*)dout;
#pragma unroll
            for (int r = 0; r < 16; ++r) o[(size_t)(row0 + r) * DD + t] = f2bf(acc[r] + bv);
        }
    }
}

// ---------------------------------------------------------------------------
// Fused masked attention. Scores are bounded (inputs ~N(0,1), 0.02-scale
// weights), so no max-shift: e = exp(s); Z = sum e (all), S = sum e*mask,
// out = (sum e*mask*V) / (S + 1e-8*Z)  — exactly matches reference
// softmax -> mask -> renormalize algebra.
// One block per (b, h, 32-row tile); threads (r = t/8, g = t%8).
// ---------------------------------------------------------------------------
__global__ __launch_bounds__(256) void k_attn(
    const float* __restrict__ Q, const float* __restrict__ K,
    const float* __restrict__ V,
    const unsigned* __restrict__ edgebits, const unsigned* __restrict__ colbits,
    float* __restrict__ attnout)
{
    int rt = blockIdx.x;            // row tile 0..63
    int h  = blockIdx.y;
    int b  = blockIdx.z;
    int t  = threadIdx.x;
    int r  = t >> 3;                // 0..31 row within tile
    int g  = t & 7;                 // 0..7 group
    __shared__ float Qs[32][33], Ks[32][33], Vs[32][33], Wt[32][33];

    const size_t headoff = ((size_t)(b * HH + h)) * NN * HD;
    const int r0 = rt * 32;
    const float qscale = 0.17677669529663687f;   // 1/sqrt(32)

    {   // load Q tile: each thread 4 consecutive floats
        int rr = t >> 3, j = (t & 7) * 4;
        float4 q4 = *reinterpret_cast<const float4*>(Q + headoff + (size_t)(r0 + rr) * HD + j);
        Qs[rr][j + 0] = q4.x * qscale;
        Qs[rr][j + 1] = q4.y * qscale;
        Qs[rr][j + 2] = q4.z * qscale;
        Qs[rr][j + 3] = q4.w * qscale;
    }

    float Zp = 0.f, Sp = 0.f;
    float acc[4] = {0.f, 0.f, 0.f, 0.f};

    for (int ct = 0; ct < NN / 32; ++ct) {
        __syncthreads();            // prior-tile Ks/Vs/Wt readers done
        {
            int rr = t >> 3, j = (t & 7) * 4;
            size_t off = headoff + (size_t)(ct * 32 + rr) * HD + j;
            float4 k4 = *reinterpret_cast<const float4*>(K + off);
            float4 v4 = *reinterpret_cast<const float4*>(V + off);
            Ks[rr][j + 0] = k4.x; Ks[rr][j + 1] = k4.y;
            Ks[rr][j + 2] = k4.z; Ks[rr][j + 3] = k4.w;
            Vs[rr][j + 0] = v4.x; Vs[rr][j + 1] = v4.y;
            Vs[rr][j + 2] = v4.z; Vs[rr][j + 3] = v4.w;
        }
        __syncthreads();

        unsigned mw = edgebits[(r0 + r) * 64 + ct] | colbits[b * 64 + ct];

#pragma unroll
        for (int ci = 0; ci < 4; ++ci) {
            int c = g * 4 + ci;
            float s = 0.f;
#pragma unroll
            for (int k2 = 0; k2 < 32; ++k2) s += Qs[r][k2] * Ks[c][k2];
            float e = __expf(s);
            float me = ((mw >> c) & 1) ? e : 0.f;
            Zp += e; Sp += me;
            Wt[r][c] = me;
        }
        __syncthreads();            // Wt visible across row groups
        for (int c = 0; c < 32; ++c) {
            float w = Wt[r][c];
#pragma unroll
            for (int i = 0; i < 4; ++i) acc[i] += w * Vs[c][g * 4 + i];
        }
    }

    // reduce Z,S across the 8 lanes of this row group
#pragma unroll
    for (int o = 1; o < 8; o <<= 1) {
        Zp += __shfl_xor(Zp, o, 64);
        Sp += __shfl_xor(Sp, o, 64);
    }
    float inv = 1.f / (Sp + 1e-8f * Zp);
    int n = r0 + r;
    float4 ov = make_float4(acc[0] * inv, acc[1] * inv, acc[2] * inv, acc[3] * inv);
    *reinterpret_cast<float4*>(attnout + ((size_t)(b * NN + n)) * DD + h * HD + g * 4) = ov;
}

// ---------------------------------------------------------------------------
extern "C" void kernel_launch(void* const* d_in, const int* in_sizes, int n_in,
                              void* d_out, int out_size, void* d_ws, size_t ws_size,
                              hipStream_t stream)
{
    const void* x   = d_in[0];
    const int*  ei  = (const int*)d_in[1];

    // workspace layout (bytes, 256-aligned blocks)
    char* ws = (char*)d_ws;
    constexpr size_t OFF_FLAG = 0;
    constexpr size_t OFF_EB   = 256;
    constexpr size_t OFF_CB   = OFF_EB  + (size_t)NN * 64 * 4;      // 524544
    constexpr size_t OFF_TOPO = OFF_CB  + (size_t)BB * 64 * 4;      // 525056
    constexpr size_t OFF_XF   = OFF_TOPO + (size_t)BB * NN * 4;     // 541440
    constexpr size_t OFF_QW   = OFF_XF  + (size_t)BB * NN * DD * 4;
    constexpr size_t OFF_KW   = OFF_QW  + (size_t)DD * DD * 4;
    constexpr size_t OFF_VW   = OFF_KW  + (size_t)DD * DD * 4;
    constexpr size_t OFF_OW   = OFF_VW  + (size_t)DD * DD * 4;
    constexpr size_t OFF_QB   = OFF_OW  + (size_t)DD * DD * 4;
    constexpr size_t OFF_KB   = OFF_QB  + (size_t)DD * 4;
    constexpr size_t OFF_VB   = OFF_KB  + (size_t)DD * 4;
    constexpr size_t OFF_OB   = OFF_VB  + (size_t)DD * 4;
    constexpr size_t OFF_G1W  = OFF_OB  + (size_t)DD * 4;
    constexpr size_t OFF_G1B  = OFF_G1W + (size_t)(DD / 2) * DD * 4;
    constexpr size_t OFF_G2W  = OFF_G1B + (size_t)(DD / 2) * 4;
    constexpr size_t OFF_G2B  = OFF_G2W + (size_t)(DD / 2) * 4;
    constexpr size_t OFF_Q    = OFF_G2B + 256;
    constexpr size_t OFF_K    = OFF_Q   + (size_t)BB * NN * DD * 4;
    constexpr size_t OFF_V    = OFF_K   + (size_t)BB * NN * DD * 4;
    constexpr size_t OFF_AO   = OFF_V   + (size_t)BB * NN * DD * 4;

    int*      flag     = (int*)(ws + OFF_FLAG);
    unsigned* edgebits = (unsigned*)(ws + OFF_EB);
    unsigned* colbits  = (unsigned*)(ws + OFF_CB);
    float*    topo     = (float*)(ws + OFF_TOPO);
    float*    xF       = (float*)(ws + OFF_XF);
    float*    qwF      = (float*)(ws + OFF_QW);
    float*    kwF      = (float*)(ws + OFF_KW);
    float*    vwF      = (float*)(ws + OFF_VW);
    float*    owF      = (float*)(ws + OFF_OW);
    float*    qbF      = (float*)(ws + OFF_QB);
    float*    kbF      = (float*)(ws + OFF_KB);
    float*    vbF      = (float*)(ws + OFF_VB);
    float*    obF      = (float*)(ws + OFF_OB);
    float*    g1wF     = (float*)(ws + OFF_G1W);
    float*    g1bF     = (float*)(ws + OFF_G1B);
    float*    g2wF     = (float*)(ws + OFF_G2W);
    float*    g2bF     = (float*)(ws + OFF_G2B);
    float*    Qf       = (float*)(ws + OFF_Q);
    float*    Kf       = (float*)(ws + OFF_K);
    float*    Vf       = (float*)(ws + OFF_V);
    float*    AOf      = (float*)(ws + OFF_AO);

    // zero flag+edge/col bitmasks
    hipMemsetAsync(d_ws, 0, OFF_TOPO, stream);

    k_detect<<<dim3(1), dim3(256), 0, stream>>>(x, flag);

    ConvArgs ca;
    const int din_idx[NT] = {0, 2, 4, 6, 8, 3, 5, 7, 9, 10, 11, 12, 13};
    float* dsts[NT] = {xF, qwF, kwF, vwF, owF, qbF, kbF, vbF, obF, g1wF, g1bF, g2wF, g2bF};
    for (int i = 0; i < NT; ++i) {
        ca.src[i] = d_in[din_idx[i]];
        ca.dst[i] = dsts[i];
        ca.n[i]   = in_sizes[din_idx[i]];
    }
    k_convert<<<dim3(512, NT), dim3(256), 0, stream>>>(ca, flag);

    k_topo<<<dim3(BB * NN), dim3(128), 0, stream>>>(xF, g1wF, g1bF, g2wF, g2bF, topo);
    k_rank<<<dim3(NN / 256, BB), dim3(256), 0, stream>>>(topo, colbits);
    k_edges<<<dim3(EE / 256), dim3(256), 0, stream>>>(ei, edgebits);
    k_maskout<<<dim3(BB * NN), dim3(256), 0, stream>>>(edgebits, colbits, d_out, flag);

    k_gemm<<<dim3((BB * NN) / 16), dim3(256), 0, stream>>>(xF, qwF, qbF, Qf, d_out, flag, 0);
    k_gemm<<<dim3((BB * NN) / 16), dim3(256), 0, stream>>>(xF, kwF, kbF, Kf, d_out, flag, 0);
    k_gemm<<<dim3((BB * NN) / 16), dim3(256), 0, stream>>>(xF, vwF, vbF, Vf, d_out, flag, 0);

    k_attn<<<dim3(NN / 32, HH, BB), dim3(256), 0, stream>>>(Qf, Kf, Vf, edgebits, colbits, AOf);

    k_gemm<<<dim3((BB * NN) / 16), dim3(256), 0, stream>>>(AOf, owF, obF, AOf, d_out, flag, 1);
}

// Round 3
// 789.574 us; speedup vs baseline: 1.2922x; 1.2922x over previous
//
#include <hip/hip_runtime.h>
#include <hip/hip_bf16.h>

// Problem constants (B,N,D,H,E from reference; hd = D/H)
#define BB   2
#define NN   2048
#define DD   256
#define HH   8
#define HD   32
#define EE   65536
#define KTOP 1024   // N * (1 - 0.5)
#define NT   13     // float tensors to canonicalize

typedef __attribute__((ext_vector_type(8))) short bf16x8;
typedef __attribute__((ext_vector_type(4))) float f32x4;

__device__ __forceinline__ float bf2f(unsigned short u) {
    return __uint_as_float(((unsigned)u) << 16);
}
__device__ __forceinline__ unsigned short f2bf(float f) {
    __hip_bfloat16 h = __float2bfloat16(f);
    return *reinterpret_cast<unsigned short*>(&h);
}

// ---------------------------------------------------------------------------
// Dtype detector: read first 64K ushorts of x as bf16. fp32 data misread as
// bf16 has random exponents in the odd halves -> max blows past 1e10.
// flag: 1 = fp32, 0 = bf16.
// ---------------------------------------------------------------------------
__global__ __launch_bounds__(256) void k_detect(const void* __restrict__ x, int* __restrict__ flag)
{
    __shared__ float red[256];
    const unsigned short* u = (const unsigned short*)x;
    float mx = 0.f;
    for (int i = threadIdx.x; i < 65536; i += 256) {
        float v = fabsf(bf2f(u[i]));
        if (!(v <= 1e10f)) v = 1e30f;       // NaN / inf / huge -> big
        mx = fmaxf(mx, v);
    }
    red[threadIdx.x] = mx;
    __syncthreads();
    for (int s = 128; s > 0; s >>= 1) {
        if (threadIdx.x < s) red[threadIdx.x] = fmaxf(red[threadIdx.x], red[threadIdx.x + s]);
        __syncthreads();
    }
    if (threadIdx.x == 0) *flag = (red[0] > 1e10f) ? 1 : 0;
}

// ---------------------------------------------------------------------------
// Canonicalize all float tensors to fp32 in workspace.
// ---------------------------------------------------------------------------
struct ConvArgs {
    const void* src[NT];
    float*      dst[NT];
    int         n[NT];
};

__global__ __launch_bounds__(256) void k_convert(ConvArgs a, const int* __restrict__ flag)
{
    int t = blockIdx.y;
    int n = a.n[t];
    int fp = *flag;
    const float* sf = (const float*)a.src[t];
    const unsigned short* sb = (const unsigned short*)a.src[t];
    float* d = a.dst[t];
    for (int i = blockIdx.x * 256 + threadIdx.x; i < n; i += gridDim.x * 256)
        d[i] = fp ? sf[i] : bf2f(sb[i]);
}

// ---------------------------------------------------------------------------
// topo[b,n] = g2 @ relu(g1 @ x[b,n] + g1_b) + g2_b      (hidden = 128)
// ---------------------------------------------------------------------------
__global__ __launch_bounds__(128) void k_topo(
    const float* __restrict__ x,
    const float* __restrict__ g1w, const float* __restrict__ g1b,
    const float* __restrict__ g2w, const float* __restrict__ g2b,
    float* __restrict__ topo)
{
    int row = blockIdx.x;            // b*N + n
    int t   = threadIdx.x;           // 0..127 (hidden unit)
    __shared__ float xs[DD];
    __shared__ float red[128];
    for (int i = t; i < DD; i += 128) xs[i] = x[(size_t)row * DD + i];
    __syncthreads();
    float acc = 0.f;
    const float* wrow = g1w + (size_t)t * DD;
    for (int k = 0; k < DD; ++k) acc += xs[k] * wrow[k];
    acc += g1b[t];
    acc = fmaxf(acc, 0.f);
    acc *= g2w[t];
    red[t] = acc;
    __syncthreads();
    for (int s = 64; s > 0; s >>= 1) { if (t < s) red[t] += red[t + s]; __syncthreads(); }
    if (t == 0) topo[row] = red[0] + g2b[0];
}

// ---------------------------------------------------------------------------
// Stable top-k -> column bit mask (jax.lax.top_k stable-tie semantics).
// ---------------------------------------------------------------------------
__global__ __launch_bounds__(256) void k_rank(
    const float* __restrict__ topo, unsigned* __restrict__ colbits)
{
    int b = blockIdx.y;
    int m = blockIdx.x * 256 + threadIdx.x;
    __shared__ float tl[NN];
    for (int i = threadIdx.x; i < NN; i += 256) tl[i] = topo[b * NN + i];
    __syncthreads();
    float v = tl[m];
    int rank = 0;
    for (int j = 0; j < NN; ++j) {
        float vj = tl[j];
        rank += (vj > v) || (vj == v && j < m);
    }
    if (rank < KTOP) atomicOr(&colbits[b * 64 + (m >> 5)], 1u << (m & 31));
}

// ---------------------------------------------------------------------------
// Edge bitmask: edgebits[n][m/32] |= bit(m)
// ---------------------------------------------------------------------------
__global__ __launch_bounds__(256) void k_edges(
    const int* __restrict__ ei, unsigned* __restrict__ edgebits)
{
    int e = blockIdx.x * 256 + threadIdx.x;
    if (e >= EE) return;
    int r = ei[e];
    int c = ei[EE + e];
    atomicOr(&edgebits[r * 64 + (c >> 5)], 1u << (c & 31));
}

// ---------------------------------------------------------------------------
// sparse_mask output [B,H,N,N]: value = edge|col bit. Store dtype per flag.
// ---------------------------------------------------------------------------
__global__ __launch_bounds__(256) void k_maskout(
    const unsigned* __restrict__ edgebits, const unsigned* __restrict__ colbits,
    void* __restrict__ dout, const int* __restrict__ flag)
{
    int row = blockIdx.x;                 // b*N + n
    int b = row / NN, n = row % NN;
    int t = threadIdx.x;                  // covers cols t*8 .. t*8+7
    unsigned w = edgebits[n * 64 + (t >> 2)] | colbits[b * 64 + (t >> 2)];
    unsigned bits = (w >> ((t & 3) * 8)) & 0xFFu;
    if (*flag) {
        float v[8];
#pragma unroll
        for (int i = 0; i < 8; ++i) v[i] = ((bits >> i) & 1) ? 1.f : 0.f;
        float* base = (float*)dout + (size_t)BB * NN * DD;
#pragma unroll
        for (int h = 0; h < HH; ++h) {
            size_t idx = ((((size_t)(b * HH + h)) * NN + n) * NN) + (size_t)t * 8;
            *reinterpret_cast<float4*>(base + idx)     = make_float4(v[0], v[1], v[2], v[3]);
            *reinterpret_cast<float4*>(base + idx + 4) = make_float4(v[4], v[5], v[6], v[7]);
        }
    } else {
        unsigned v[8];
#pragma unroll
        for (int i = 0; i < 8; ++i) v[i] = ((bits >> i) & 1) ? 0x3F80u : 0u;
        uint4 o4;
        o4.x = v[0] | (v[1] << 16);
        o4.y = v[2] | (v[3] << 16);
        o4.z = v[4] | (v[5] << 16);
        o4.w = v[6] | (v[7] << 16);
        unsigned short* base = (unsigned short*)dout + (size_t)BB * NN * DD;
#pragma unroll
        for (int h = 0; h < HH; ++h) {
            size_t idx = ((((size_t)(b * HH + h)) * NN + n) * NN) + (size_t)t * 8;
            *reinterpret_cast<uint4*>(base + idx) = o4;
        }
    }
}

// ---------------------------------------------------------------------------
// GEMM: out[row, col] = X[row,:] . W[col,:] + bias[col]
// mode 0: bf16 head layout [b][h][n][j], value*(scale)   (Q, K)
// mode 2: bf16 transposed head layout [b][h][j][n]       (V -> Vt)
// mode 1: store to d_out (dtype per flag), row-major
// ---------------------------------------------------------------------------
__global__ __launch_bounds__(256) void k_gemm(
    const float* __restrict__ X, const float* __restrict__ W,
    const float* __restrict__ bias, void* __restrict__ outB,
    void* __restrict__ dout, const int* __restrict__ flag, int mode, float scale)
{
    __shared__ float xs[16][DD];
    __shared__ float wt[16][257];
    int t = threadIdx.x;
    int row0 = blockIdx.x * 16;
    {   // vectorized X tile load
        const float4* X4 = reinterpret_cast<const float4*>(X + (size_t)row0 * DD);
        for (int i = t; i < 16 * 64; i += 256) {
            int r = i >> 6, k4 = i & 63;
            *reinterpret_cast<float4*>(&xs[r][k4 * 4]) = X4[(size_t)r * 64 + k4];
        }
    }
    float acc[16];
#pragma unroll
    for (int r = 0; r < 16; ++r) acc[r] = 0.f;

    for (int kt = 0; kt < DD; kt += 16) {
        __syncthreads();
        for (int i = t; i < 256 * 16; i += 256) {
            int nn = i >> 4, kk = i & 15;
            wt[kk][nn] = W[(size_t)nn * DD + kt + kk];
        }
        __syncthreads();
#pragma unroll
        for (int kk = 0; kk < 16; ++kk) {
            float wv = wt[kk][t];
#pragma unroll
            for (int r = 0; r < 16; ++r) acc[r] += xs[r][kt + kk] * wv;
        }
    }
    float bv = bias[t];
    if (mode == 0) {
        unsigned short* o = (unsigned short*)outB;
        int hh = t >> 5, j = t & 31;
#pragma unroll
        for (int r = 0; r < 16; ++r) {
            int row = row0 + r;
            int b = row / NN, n2 = row % NN;
            o[(((size_t)(b * HH + hh)) * NN + n2) * HD + j] = f2bf((acc[r] + bv) * scale);
        }
    } else if (mode == 2) {
        unsigned short* o = (unsigned short*)outB;
        int hh = t >> 5, j = t & 31;
#pragma unroll
        for (int r = 0; r < 16; ++r) {
            int row = row0 + r;
            int b = row / NN, n2 = row % NN;
            o[(((size_t)(b * HH + hh)) * HD + j) * NN + n2] = f2bf(acc[r] + bv);
        }
    } else {
        if (*flag) {
            float* o = (float*)dout;
#pragma unroll
            for (int r = 0; r < 16; ++r) o[(size_t)(row0 + r) * DD + t] = acc[r] + bv;
        } else {
            unsigned short* o = (unsigned short*)dout;
#pragma unroll
            for (int r = 0; r < 16; ++r) o[(size_t)(row0 + r) * DD + t] = f2bf(acc[r] + bv);
        }
    }
}

// ---------------------------------------------------------------------------
// Fused masked attention, MFMA version.
// sparse_attn = e*mask / (S_mask + 1e-8*Z); no max-shift (scores bounded).
// Block = 4 waves, 64 Q rows (wave w: rows r0+w*16..+16). Loop 64 chunks of
// 32 cols. Per chunk per wave: 2 QK mfma (A=Q frag from global, B=K frag
// from global), exp+mask, P->LDS (bf16, per-wave double buffer, stride 40),
// P A-frag read, 2 PV mfma with B from Vt[d][n] (global, contiguous).
// Z/S accumulate per C-reg; xor-shuffle reduce over lanes 1,2,4,8 at end.
// ---------------------------------------------------------------------------
__global__ __launch_bounds__(256) void k_attn(
    const unsigned short* __restrict__ Qbf, const unsigned short* __restrict__ Kbf,
    const unsigned short* __restrict__ Vt,
    const unsigned* __restrict__ edgebits, const unsigned* __restrict__ colbits,
    float* __restrict__ attnout)
{
    int rt = blockIdx.x;            // 64-row tile 0..31
    int h  = blockIdx.y;
    int b  = blockIdx.z;
    int t  = threadIdx.x;
    int w    = t >> 6;              // wave 0..3
    int lane = t & 63;
    int q4   = lane >> 4;           // quad 0..3
    int l16  = lane & 15;

    __shared__ unsigned mw[64][65];            // mask words for this block's rows
    __shared__ short Pl[4][2][16 * 40];        // [wave][buf][row*40 + col]

    const int r0 = rt * 64;
    for (int i = t; i < 64 * 64; i += 256) {
        int r = i >> 6, wd = i & 63;
        mw[r][wd] = edgebits[(r0 + r) * 64 + wd] | colbits[b * 64 + wd];
    }
    __syncthreads();

    const unsigned short* Qp = Qbf + ((size_t)(b * HH + h)) * NN * HD;
    const unsigned short* Kp = Kbf + ((size_t)(b * HH + h)) * NN * HD;
    const unsigned short* Vp = Vt  + ((size_t)(b * HH + h)) * HD * NN;

    // Q A-frag: rows r0 + w*16 + l16, k = q4*8 .. +8 (contiguous 16B)
    bf16x8 afrag = *reinterpret_cast<const bf16x8*>(Qp + (size_t)(r0 + w * 16 + l16) * HD + q4 * 8);

    f32x4 O0 = {0.f, 0.f, 0.f, 0.f}, O1 = {0.f, 0.f, 0.f, 0.f};
    float Zp[4] = {0.f, 0.f, 0.f, 0.f}, Sp[4] = {0.f, 0.f, 0.f, 0.f};

    for (int ch = 0; ch < 64; ++ch) {
        int n0 = ch * 32;
        bf16x8 kb0 = *reinterpret_cast<const bf16x8*>(Kp + (size_t)(n0 + l16) * HD + q4 * 8);
        bf16x8 kb1 = *reinterpret_cast<const bf16x8*>(Kp + (size_t)(n0 + 16 + l16) * HD + q4 * 8);
        f32x4 s0 = __builtin_amdgcn_mfma_f32_16x16x32_bf16(afrag, kb0, (f32x4){0.f,0.f,0.f,0.f}, 0, 0, 0);
        f32x4 s1 = __builtin_amdgcn_mfma_f32_16x16x32_bf16(afrag, kb1, (f32x4){0.f,0.f,0.f,0.f}, 0, 0, 0);

        short* P = &Pl[w][ch & 1][0];
#pragma unroll
        for (int i = 0; i < 4; ++i) {
            int rl = w * 16 + q4 * 4 + i;          // block-local row
            unsigned wdv = mw[rl][ch];
            float e0 = __expf(s0[i]);
            float e1 = __expf(s1[i]);
            float m0 = ((wdv >> l16) & 1u) ? e0 : 0.f;
            float m1 = ((wdv >> (16 + l16)) & 1u) ? e1 : 0.f;
            Zp[i] += e0 + e1;
            Sp[i] += m0 + m1;
            int prow = q4 * 4 + i;
            P[prow * 40 + l16]      = (short)f2bf(m0);
            P[prow * 40 + 16 + l16] = (short)f2bf(m1);
        }
        asm volatile("s_waitcnt lgkmcnt(0)" ::: "memory");
        bf16x8 pfrag = *reinterpret_cast<const bf16x8*>(P + l16 * 40 + q4 * 8);
        bf16x8 vb0 = *reinterpret_cast<const bf16x8*>(Vp + (size_t)l16 * NN + n0 + q4 * 8);
        bf16x8 vb1 = *reinterpret_cast<const bf16x8*>(Vp + (size_t)(16 + l16) * NN + n0 + q4 * 8);
        O0 = __builtin_amdgcn_mfma_f32_16x16x32_bf16(pfrag, vb0, O0, 0, 0, 0);
        O1 = __builtin_amdgcn_mfma_f32_16x16x32_bf16(pfrag, vb1, O1, 0, 0, 0);
    }

    // reduce Z,S across the 16 lanes sharing q4 (xor bits 0..3)
#pragma unroll
    for (int o = 1; o < 16; o <<= 1) {
#pragma unroll
        for (int i = 0; i < 4; ++i) {
            Zp[i] += __shfl_xor(Zp[i], o, 64);
            Sp[i] += __shfl_xor(Sp[i], o, 64);
        }
    }
#pragma unroll
    for (int i = 0; i < 4; ++i) {
        float inv = 1.f / (Sp[i] + 1e-8f * Zp[i]);
        int n = r0 + w * 16 + q4 * 4 + i;
        float* op = attnout + ((size_t)(b * NN + n)) * DD + h * HD;
        op[l16]      = O0[i] * inv;
        op[16 + l16] = O1[i] * inv;
    }
}

// ---------------------------------------------------------------------------
extern "C" void kernel_launch(void* const* d_in, const int* in_sizes, int n_in,
                              void* d_out, int out_size, void* d_ws, size_t ws_size,
                              hipStream_t stream)
{
    const void* x   = d_in[0];
    const int*  ei  = (const int*)d_in[1];

    // workspace layout (bytes)
    char* ws = (char*)d_ws;
    constexpr size_t OFF_FLAG = 0;
    constexpr size_t OFF_EB   = 256;
    constexpr size_t OFF_CB   = OFF_EB  + (size_t)NN * 64 * 4;
    constexpr size_t OFF_TOPO = OFF_CB  + (size_t)BB * 64 * 4;
    constexpr size_t OFF_XF   = OFF_TOPO + (size_t)BB * NN * 4;
    constexpr size_t OFF_QW   = OFF_XF  + (size_t)BB * NN * DD * 4;
    constexpr size_t OFF_KW   = OFF_QW  + (size_t)DD * DD * 4;
    constexpr size_t OFF_VW   = OFF_KW  + (size_t)DD * DD * 4;
    constexpr size_t OFF_OW   = OFF_VW  + (size_t)DD * DD * 4;
    constexpr size_t OFF_QB   = OFF_OW  + (size_t)DD * DD * 4;
    constexpr size_t OFF_KB   = OFF_QB  + (size_t)DD * 4;
    constexpr size_t OFF_VB   = OFF_KB  + (size_t)DD * 4;
    constexpr size_t OFF_OB   = OFF_VB  + (size_t)DD * 4;
    constexpr size_t OFF_G1W  = OFF_OB  + (size_t)DD * 4;
    constexpr size_t OFF_G1B  = OFF_G1W + (size_t)(DD / 2) * DD * 4;
    constexpr size_t OFF_G2W  = OFF_G1B + (size_t)(DD / 2) * 4;
    constexpr size_t OFF_G2B  = OFF_G2W + (size_t)(DD / 2) * 4;
    constexpr size_t OFF_Q    = OFF_G2B + 256;                        // bf16
    constexpr size_t OFF_K    = OFF_Q   + (size_t)BB * NN * DD * 2;   // bf16
    constexpr size_t OFF_VT   = OFF_K   + (size_t)BB * NN * DD * 2;   // bf16 transposed
    constexpr size_t OFF_AO   = OFF_VT  + (size_t)BB * NN * DD * 2;   // fp32

    int*      flag     = (int*)(ws + OFF_FLAG);
    unsigned* edgebits = (unsigned*)(ws + OFF_EB);
    unsigned* colbits  = (unsigned*)(ws + OFF_CB);
    float*    topo     = (float*)(ws + OFF_TOPO);
    float*    xF       = (float*)(ws + OFF_XF);
    float*    qwF      = (float*)(ws + OFF_QW);
    float*    kwF      = (float*)(ws + OFF_KW);
    float*    vwF      = (float*)(ws + OFF_VW);
    float*    owF      = (float*)(ws + OFF_OW);
    float*    qbF      = (float*)(ws + OFF_QB);
    float*    kbF      = (float*)(ws + OFF_KB);
    float*    vbF      = (float*)(ws + OFF_VB);
    float*    obF      = (float*)(ws + OFF_OB);
    float*    g1wF     = (float*)(ws + OFF_G1W);
    float*    g1bF     = (float*)(ws + OFF_G1B);
    float*    g2wF     = (float*)(ws + OFF_G2W);
    float*    g2bF     = (float*)(ws + OFF_G2B);
    unsigned short* Qbf = (unsigned short*)(ws + OFF_Q);
    unsigned short* Kbf = (unsigned short*)(ws + OFF_K);
    unsigned short* Vtb = (unsigned short*)(ws + OFF_VT);
    float*    AOf      = (float*)(ws + OFF_AO);

    // zero flag + edge/col bitmasks
    hipMemsetAsync(d_ws, 0, OFF_TOPO, stream);

    k_detect<<<dim3(1), dim3(256), 0, stream>>>(x, flag);

    ConvArgs ca;
    const int din_idx[NT] = {0, 2, 4, 6, 8, 3, 5, 7, 9, 10, 11, 12, 13};
    float* dsts[NT] = {xF, qwF, kwF, vwF, owF, qbF, kbF, vbF, obF, g1wF, g1bF, g2wF, g2bF};
    for (int i = 0; i < NT; ++i) {
        ca.src[i] = d_in[din_idx[i]];
        ca.dst[i] = dsts[i];
        ca.n[i]   = in_sizes[din_idx[i]];
    }
    k_convert<<<dim3(64, NT), dim3(256), 0, stream>>>(ca, flag);

    k_topo<<<dim3(BB * NN), dim3(128), 0, stream>>>(xF, g1wF, g1bF, g2wF, g2bF, topo);
    k_rank<<<dim3(NN / 256, BB), dim3(256), 0, stream>>>(topo, colbits);
    k_edges<<<dim3(EE / 256), dim3(256), 0, stream>>>(ei, edgebits);
    k_maskout<<<dim3(BB * NN), dim3(256), 0, stream>>>(edgebits, colbits, d_out, flag);

    const float qscale = 0.17677669529663687f;   // 1/sqrt(32)
    k_gemm<<<dim3((BB * NN) / 16), dim3(256), 0, stream>>>(xF, qwF, qbF, Qbf, d_out, flag, 0, qscale);
    k_gemm<<<dim3((BB * NN) / 16), dim3(256), 0, stream>>>(xF, kwF, kbF, Kbf, d_out, flag, 0, 1.0f);
    k_gemm<<<dim3((BB * NN) / 16), dim3(256), 0, stream>>>(xF, vwF, vbF, Vtb, d_out, flag, 2, 1.0f);

    k_attn<<<dim3(NN / 64, HH, BB), dim3(256), 0, stream>>>(Qbf, Kbf, Vtb, edgebits, colbits, AOf);

    k_gemm<<<dim3((BB * NN) / 16), dim3(256), 0, stream>>>(AOf, owF, obF, nullptr, d_out, flag, 1, 1.0f);
}

// Round 4
// 596.183 us; speedup vs baseline: 1.7114x; 1.3244x over previous
//
#include <hip/hip_runtime.h>
#include <hip/hip_bf16.h>

// Problem constants (B,N,D,H,E from reference; hd = D/H)
#define BB   2
#define NN   2048
#define DD   256
#define HH   8
#define HD   32
#define EE   65536
#define KTOP 1024   // N * (1 - 0.5)
#define NT   13     // float tensors to canonicalize

typedef __attribute__((ext_vector_type(8))) short bf16x8;
typedef __attribute__((ext_vector_type(4))) float f32x4;

__device__ __forceinline__ float bf2f(unsigned short u) {
    return __uint_as_float(((unsigned)u) << 16);
}
__device__ __forceinline__ unsigned short f2bf(float f) {
    __hip_bfloat16 h = __float2bfloat16(f);
    return *reinterpret_cast<unsigned short*>(&h);
}

// ---------------------------------------------------------------------------
// Dtype detector: read first 64K ushorts of x as bf16. fp32 data misread as
// bf16 has random exponents in the odd halves -> max blows past 1e10.
// flag: 1 = fp32, 0 = bf16.
// ---------------------------------------------------------------------------
__global__ __launch_bounds__(256) void k_detect(const void* __restrict__ x, int* __restrict__ flag)
{
    __shared__ float red[256];
    const unsigned short* u = (const unsigned short*)x;
    float mx = 0.f;
    for (int i = threadIdx.x; i < 65536; i += 256) {
        float v = fabsf(bf2f(u[i]));
        if (!(v <= 1e10f)) v = 1e30f;       // NaN / inf / huge -> big
        mx = fmaxf(mx, v);
    }
    red[threadIdx.x] = mx;
    __syncthreads();
    for (int s = 128; s > 0; s >>= 1) {
        if (threadIdx.x < s) red[threadIdx.x] = fmaxf(red[threadIdx.x], red[threadIdx.x + s]);
        __syncthreads();
    }
    if (threadIdx.x == 0) *flag = (red[0] > 1e10f) ? 1 : 0;
}

// ---------------------------------------------------------------------------
// Canonicalize float tensors to fp32 (+ optional bf16 copy) in workspace.
// ---------------------------------------------------------------------------
struct ConvArgs {
    const void*     src[NT];
    float*          dst[NT];
    unsigned short* dstB[NT];   // nullable: also emit bf16
    int             n[NT];
};

__global__ __launch_bounds__(256) void k_convert(ConvArgs a, const int* __restrict__ flag)
{
    int t = blockIdx.y;
    int n = a.n[t];
    int fp = *flag;
    const float* sf = (const float*)a.src[t];
    const unsigned short* sb = (const unsigned short*)a.src[t];
    float* d = a.dst[t];
    unsigned short* db = a.dstB[t];
    for (int i = blockIdx.x * 256 + threadIdx.x; i < n; i += gridDim.x * 256) {
        float v = fp ? sf[i] : bf2f(sb[i]);
        d[i] = v;
        if (db) db[i] = f2bf(v);
    }
}

// ---------------------------------------------------------------------------
// topo[b,n] = g2 @ relu(g1 @ x[b,n] + g1_b) + g2_b      (hidden = 128)
// Kept pure fp32: top-k selection is discrete; bf16 intermediates would
// flip ranks (err ~3e-4 vs order-stat gaps ~1.5e-4).
// ---------------------------------------------------------------------------
__global__ __launch_bounds__(128) void k_topo(
    const float* __restrict__ x,
    const float* __restrict__ g1w, const float* __restrict__ g1b,
    const float* __restrict__ g2w, const float* __restrict__ g2b,
    float* __restrict__ topo)
{
    int row = blockIdx.x;            // b*N + n
    int t   = threadIdx.x;           // 0..127 (hidden unit)
    __shared__ float xs[DD];
    __shared__ float red[128];
    for (int i = t; i < DD; i += 128) xs[i] = x[(size_t)row * DD + i];
    __syncthreads();
    float acc = 0.f;
    const float* wrow = g1w + (size_t)t * DD;
    for (int k = 0; k < DD; ++k) acc += xs[k] * wrow[k];
    acc += g1b[t];
    acc = fmaxf(acc, 0.f);
    acc *= g2w[t];
    red[t] = acc;
    __syncthreads();
    for (int s = 64; s > 0; s >>= 1) { if (t < s) red[t] += red[t + s]; __syncthreads(); }
    if (t == 0) topo[row] = red[0] + g2b[0];
}

// ---------------------------------------------------------------------------
// Stable top-k -> column bit mask (jax.lax.top_k stable-tie semantics).
// ---------------------------------------------------------------------------
__global__ __launch_bounds__(256) void k_rank(
    const float* __restrict__ topo, unsigned* __restrict__ colbits)
{
    int b = blockIdx.y;
    int m = blockIdx.x * 256 + threadIdx.x;
    __shared__ float tl[NN];
    for (int i = threadIdx.x; i < NN; i += 256) tl[i] = topo[b * NN + i];
    __syncthreads();
    float v = tl[m];
    int rank = 0;
    for (int j = 0; j < NN; ++j) {
        float vj = tl[j];
        rank += (vj > v) || (vj == v && j < m);
    }
    if (rank < KTOP) atomicOr(&colbits[b * 64 + (m >> 5)], 1u << (m & 31));
}

// ---------------------------------------------------------------------------
// Edge bitmask: edgebits[n][m/32] |= bit(m)
// ---------------------------------------------------------------------------
__global__ __launch_bounds__(256) void k_edges(
    const int* __restrict__ ei, unsigned* __restrict__ edgebits)
{
    int e = blockIdx.x * 256 + threadIdx.x;
    if (e >= EE) return;
    int r = ei[e];
    int c = ei[EE + e];
    atomicOr(&edgebits[r * 64 + (c >> 5)], 1u << (c & 31));
}

// ---------------------------------------------------------------------------
// sparse_mask output [B,H,N,N]: value = edge|col bit. Store dtype per flag.
// ---------------------------------------------------------------------------
__global__ __launch_bounds__(256) void k_maskout(
    const unsigned* __restrict__ edgebits, const unsigned* __restrict__ colbits,
    void* __restrict__ dout, const int* __restrict__ flag)
{
    int row = blockIdx.x;                 // b*N + n
    int b = row / NN, n = row % NN;
    int t = threadIdx.x;                  // covers cols t*8 .. t*8+7
    unsigned w = edgebits[n * 64 + (t >> 2)] | colbits[b * 64 + (t >> 2)];
    unsigned bits = (w >> ((t & 3) * 8)) & 0xFFu;
    if (*flag) {
        float v[8];
#pragma unroll
        for (int i = 0; i < 8; ++i) v[i] = ((bits >> i) & 1) ? 1.f : 0.f;
        float* base = (float*)dout + (size_t)BB * NN * DD;
#pragma unroll
        for (int h = 0; h < HH; ++h) {
            size_t idx = ((((size_t)(b * HH + h)) * NN + n) * NN) + (size_t)t * 8;
            *reinterpret_cast<float4*>(base + idx)     = make_float4(v[0], v[1], v[2], v[3]);
            *reinterpret_cast<float4*>(base + idx + 4) = make_float4(v[4], v[5], v[6], v[7]);
        }
    } else {
        unsigned v[8];
#pragma unroll
        for (int i = 0; i < 8; ++i) v[i] = ((bits >> i) & 1) ? 0x3F80u : 0u;
        uint4 o4;
        o4.x = v[0] | (v[1] << 16);
        o4.y = v[2] | (v[3] << 16);
        o4.z = v[4] | (v[5] << 16);
        o4.w = v[6] | (v[7] << 16);
        unsigned short* base = (unsigned short*)dout + (size_t)BB * NN * DD;
#pragma unroll
        for (int h = 0; h < HH; ++h) {
            size_t idx = ((((size_t)(b * HH + h)) * NN + n) * NN) + (size_t)t * 8;
            *reinterpret_cast<uint4*>(base + idx) = o4;
        }
    }
}

// ---------------------------------------------------------------------------
// MFMA projection GEMM: C[row,col] = X[row,:].W[col,:] + bias[col], all K=256.
// X bf16 [4096][256], W bf16 [256][256]. Grid (M/64, 256/64); block = 4 waves;
// wave w: rows blockIdx.x*64 + w*16, cols blockIdx.y*64 (4 n-tiles of 16).
// A/B frags are contiguous 16B global loads (A[m=lane&15][k=quad*8+j]).
// mode 0: bf16 head layout [b][h][n][j], *(scale)  (Q, K)
// mode 2: bf16 transposed head layout [b][h][j][n] (V -> Vt)
// mode 3: store to d_out (dtype per flag), row-major
// ---------------------------------------------------------------------------
__global__ __launch_bounds__(256) void k_proj(
    const unsigned short* __restrict__ Xb, const unsigned short* __restrict__ Wb,
    const float* __restrict__ bias, unsigned short* __restrict__ outB,
    void* __restrict__ dout, const int* __restrict__ flag, int mode, float scale)
{
    int t = threadIdx.x;
    int w = t >> 6, lane = t & 63, q4 = lane >> 4, l16 = lane & 15;
    int m0 = blockIdx.x * 64 + w * 16;
    int nb = blockIdx.y * 64;

    f32x4 acc[4] = {{0.f,0.f,0.f,0.f},{0.f,0.f,0.f,0.f},{0.f,0.f,0.f,0.f},{0.f,0.f,0.f,0.f}};
#pragma unroll
    for (int ks = 0; ks < 8; ++ks) {
        bf16x8 a = *reinterpret_cast<const bf16x8*>(Xb + (size_t)(m0 + l16) * DD + ks * 32 + q4 * 8);
#pragma unroll
        for (int n = 0; n < 4; ++n) {
            bf16x8 bf = *reinterpret_cast<const bf16x8*>(Wb + (size_t)(nb + n * 16 + l16) * DD + ks * 32 + q4 * 8);
            acc[n] = __builtin_amdgcn_mfma_f32_16x16x32_bf16(a, bf, acc[n], 0, 0, 0);
        }
    }

#pragma unroll
    for (int n = 0; n < 4; ++n) {
        int col = nb + n * 16 + l16;
        float bv = bias[col];
#pragma unroll
        for (int i = 0; i < 4; ++i) {
            int row = m0 + q4 * 4 + i;
            float v = (acc[n][i] + bv) * scale;
            if (mode == 0) {
                int b = row >> 11, n2 = row & (NN - 1);
                int h = col >> 5,  j  = col & (HD - 1);
                outB[(((size_t)(b * HH + h)) * NN + n2) * HD + j] = f2bf(v);
            } else if (mode == 2) {
                int b = row >> 11, n2 = row & (NN - 1);
                int h = col >> 5,  j  = col & (HD - 1);
                outB[(((size_t)(b * HH + h)) * HD + j) * NN + n2] = f2bf(v);
            } else {
                if (*flag) ((float*)dout)[(size_t)row * DD + col] = v;
                else ((unsigned short*)dout)[(size_t)row * DD + col] = f2bf(v);
            }
        }
    }
}

// ---------------------------------------------------------------------------
// Fused masked attention, MFMA (as round 3, epilogue now emits bf16 so the
// O-projection can run on MFMA).
// ---------------------------------------------------------------------------
__global__ __launch_bounds__(256) void k_attn(
    const unsigned short* __restrict__ Qbf, const unsigned short* __restrict__ Kbf,
    const unsigned short* __restrict__ Vt,
    const unsigned* __restrict__ edgebits, const unsigned* __restrict__ colbits,
    unsigned short* __restrict__ attnout)
{
    int rt = blockIdx.x;            // 64-row tile 0..31
    int h  = blockIdx.y;
    int b  = blockIdx.z;
    int t  = threadIdx.x;
    int w    = t >> 6;              // wave 0..3
    int lane = t & 63;
    int q4   = lane >> 4;           // quad 0..3
    int l16  = lane & 15;

    __shared__ unsigned mw[64][65];            // mask words for this block's rows
    __shared__ short Pl[4][2][16 * 40];        // [wave][buf][row*40 + col]

    const int r0 = rt * 64;
    for (int i = t; i < 64 * 64; i += 256) {
        int r = i >> 6, wd = i & 63;
        mw[r][wd] = edgebits[(r0 + r) * 64 + wd] | colbits[b * 64 + wd];
    }
    __syncthreads();

    const unsigned short* Qp = Qbf + ((size_t)(b * HH + h)) * NN * HD;
    const unsigned short* Kp = Kbf + ((size_t)(b * HH + h)) * NN * HD;
    const unsigned short* Vp = Vt  + ((size_t)(b * HH + h)) * HD * NN;

    bf16x8 afrag = *reinterpret_cast<const bf16x8*>(Qp + (size_t)(r0 + w * 16 + l16) * HD + q4 * 8);

    f32x4 O0 = {0.f, 0.f, 0.f, 0.f}, O1 = {0.f, 0.f, 0.f, 0.f};
    float Zp[4] = {0.f, 0.f, 0.f, 0.f}, Sp[4] = {0.f, 0.f, 0.f, 0.f};

    for (int ch = 0; ch < 64; ++ch) {
        int n0 = ch * 32;
        bf16x8 kb0 = *reinterpret_cast<const bf16x8*>(Kp + (size_t)(n0 + l16) * HD + q4 * 8);
        bf16x8 kb1 = *reinterpret_cast<const bf16x8*>(Kp + (size_t)(n0 + 16 + l16) * HD + q4 * 8);
        f32x4 s0 = __builtin_amdgcn_mfma_f32_16x16x32_bf16(afrag, kb0, (f32x4){0.f,0.f,0.f,0.f}, 0, 0, 0);
        f32x4 s1 = __builtin_amdgcn_mfma_f32_16x16x32_bf16(afrag, kb1, (f32x4){0.f,0.f,0.f,0.f}, 0, 0, 0);

        short* P = &Pl[w][ch & 1][0];
#pragma unroll
        for (int i = 0; i < 4; ++i) {
            int rl = w * 16 + q4 * 4 + i;          // block-local row
            unsigned wdv = mw[rl][ch];
            float e0 = __expf(s0[i]);
            float e1 = __expf(s1[i]);
            float m0 = ((wdv >> l16) & 1u) ? e0 : 0.f;
            float m1 = ((wdv >> (16 + l16)) & 1u) ? e1 : 0.f;
            Zp[i] += e0 + e1;
            Sp[i] += m0 + m1;
            int prow = q4 * 4 + i;
            P[prow * 40 + l16]      = (short)f2bf(m0);
            P[prow * 40 + 16 + l16] = (short)f2bf(m1);
        }
        asm volatile("s_waitcnt lgkmcnt(0)" ::: "memory");
        bf16x8 pfrag = *reinterpret_cast<const bf16x8*>(P + l16 * 40 + q4 * 8);
        bf16x8 vb0 = *reinterpret_cast<const bf16x8*>(Vp + (size_t)l16 * NN + n0 + q4 * 8);
        bf16x8 vb1 = *reinterpret_cast<const bf16x8*>(Vp + (size_t)(16 + l16) * NN + n0 + q4 * 8);
        O0 = __builtin_amdgcn_mfma_f32_16x16x32_bf16(pfrag, vb0, O0, 0, 0, 0);
        O1 = __builtin_amdgcn_mfma_f32_16x16x32_bf16(pfrag, vb1, O1, 0, 0, 0);
    }

#pragma unroll
    for (int o = 1; o < 16; o <<= 1) {
#pragma unroll
        for (int i = 0; i < 4; ++i) {
            Zp[i] += __shfl_xor(Zp[i], o, 64);
            Sp[i] += __shfl_xor(Sp[i], o, 64);
        }
    }
#pragma unroll
    for (int i = 0; i < 4; ++i) {
        float inv = 1.f / (Sp[i] + 1e-8f * Zp[i]);
        int n = r0 + w * 16 + q4 * 4 + i;
        unsigned short* op = attnout + ((size_t)(b * NN + n)) * DD + h * HD;
        op[l16]      = f2bf(O0[i] * inv);
        op[16 + l16] = f2bf(O1[i] * inv);
    }
}

// ---------------------------------------------------------------------------
extern "C" void kernel_launch(void* const* d_in, const int* in_sizes, int n_in,
                              void* d_out, int out_size, void* d_ws, size_t ws_size,
                              hipStream_t stream)
{
    const void* x   = d_in[0];
    const int*  ei  = (const int*)d_in[1];

    // workspace layout (bytes)
    char* ws = (char*)d_ws;
    constexpr size_t OFF_FLAG = 0;
    constexpr size_t OFF_EB   = 256;
    constexpr size_t OFF_CB   = OFF_EB  + (size_t)NN * 64 * 4;
    constexpr size_t OFF_TOPO = OFF_CB  + (size_t)BB * 64 * 4;
    constexpr size_t OFF_XF   = OFF_TOPO + (size_t)BB * NN * 4;
    constexpr size_t OFF_QW   = OFF_XF  + (size_t)BB * NN * DD * 4;
    constexpr size_t OFF_KW   = OFF_QW  + (size_t)DD * DD * 4;
    constexpr size_t OFF_VW   = OFF_KW  + (size_t)DD * DD * 4;
    constexpr size_t OFF_OW   = OFF_VW  + (size_t)DD * DD * 4;
    constexpr size_t OFF_QB   = OFF_OW  + (size_t)DD * DD * 4;
    constexpr size_t OFF_KB   = OFF_QB  + (size_t)DD * 4;
    constexpr size_t OFF_VB   = OFF_KB  + (size_t)DD * 4;
    constexpr size_t OFF_OB   = OFF_VB  + (size_t)DD * 4;
    constexpr size_t OFF_G1W  = OFF_OB  + (size_t)DD * 4;
    constexpr size_t OFF_G1B  = OFF_G1W + (size_t)(DD / 2) * DD * 4;
    constexpr size_t OFF_G2W  = OFF_G1B + (size_t)(DD / 2) * 4;
    constexpr size_t OFF_G2B  = OFF_G2W + (size_t)(DD / 2) * 4;
    constexpr size_t OFF_Q    = OFF_G2B + 256;                        // bf16 head layout
    constexpr size_t OFF_K    = OFF_Q   + (size_t)BB * NN * DD * 2;
    constexpr size_t OFF_VT   = OFF_K   + (size_t)BB * NN * DD * 2;   // bf16 transposed
    constexpr size_t OFF_AOB  = OFF_VT  + (size_t)BB * NN * DD * 2;   // bf16 attn out
    constexpr size_t OFF_XB   = OFF_AOB + (size_t)BB * NN * DD * 2;   // bf16 x
    constexpr size_t OFF_QWB  = OFF_XB  + (size_t)BB * NN * DD * 2;   // bf16 weights
    constexpr size_t OFF_KWB  = OFF_QWB + (size_t)DD * DD * 2;
    constexpr size_t OFF_VWB  = OFF_KWB + (size_t)DD * DD * 2;
    constexpr size_t OFF_OWB  = OFF_VWB + (size_t)DD * DD * 2;

    int*      flag     = (int*)(ws + OFF_FLAG);
    unsigned* edgebits = (unsigned*)(ws + OFF_EB);
    unsigned* colbits  = (unsigned*)(ws + OFF_CB);
    float*    topo     = (float*)(ws + OFF_TOPO);
    float*    xF       = (float*)(ws + OFF_XF);
    float*    qwF      = (float*)(ws + OFF_QW);
    float*    kwF      = (float*)(ws + OFF_KW);
    float*    vwF      = (float*)(ws + OFF_VW);
    float*    owF      = (float*)(ws + OFF_OW);
    float*    qbF      = (float*)(ws + OFF_QB);
    float*    kbF      = (float*)(ws + OFF_KB);
    float*    vbF      = (float*)(ws + OFF_VB);
    float*    obF      = (float*)(ws + OFF_OB);
    float*    g1wF     = (float*)(ws + OFF_G1W);
    float*    g1bF     = (float*)(ws + OFF_G1B);
    float*    g2wF     = (float*)(ws + OFF_G2W);
    float*    g2bF     = (float*)(ws + OFF_G2B);
    unsigned short* Qbf = (unsigned short*)(ws + OFF_Q);
    unsigned short* Kbf = (unsigned short*)(ws + OFF_K);
    unsigned short* Vtb = (unsigned short*)(ws + OFF_VT);
    unsigned short* AOb = (unsigned short*)(ws + OFF_AOB);
    unsigned short* Xbf = (unsigned short*)(ws + OFF_XB);
    unsigned short* qwB = (unsigned short*)(ws + OFF_QWB);
    unsigned short* kwB = (unsigned short*)(ws + OFF_KWB);
    unsigned short* vwB = (unsigned short*)(ws + OFF_VWB);
    unsigned short* owB = (unsigned short*)(ws + OFF_OWB);

    // zero flag + edge/col bitmasks
    hipMemsetAsync(d_ws, 0, OFF_TOPO, stream);

    k_detect<<<dim3(1), dim3(256), 0, stream>>>(x, flag);

    ConvArgs ca;
    const int din_idx[NT] = {0, 2, 4, 6, 8, 3, 5, 7, 9, 10, 11, 12, 13};
    float* dsts[NT] = {xF, qwF, kwF, vwF, owF, qbF, kbF, vbF, obF, g1wF, g1bF, g2wF, g2bF};
    unsigned short* dstsB[NT] = {Xbf, qwB, kwB, vwB, owB,
                                 nullptr, nullptr, nullptr, nullptr,
                                 nullptr, nullptr, nullptr, nullptr};
    for (int i = 0; i < NT; ++i) {
        ca.src[i]  = d_in[din_idx[i]];
        ca.dst[i]  = dsts[i];
        ca.dstB[i] = dstsB[i];
        ca.n[i]    = in_sizes[din_idx[i]];
    }
    k_convert<<<dim3(64, NT), dim3(256), 0, stream>>>(ca, flag);

    k_topo<<<dim3(BB * NN), dim3(128), 0, stream>>>(xF, g1wF, g1bF, g2wF, g2bF, topo);
    k_rank<<<dim3(NN / 256, BB), dim3(256), 0, stream>>>(topo, colbits);
    k_edges<<<dim3(EE / 256), dim3(256), 0, stream>>>(ei, edgebits);
    k_maskout<<<dim3(BB * NN), dim3(256), 0, stream>>>(edgebits, colbits, d_out, flag);

    const float qscale = 0.17677669529663687f;   // 1/sqrt(32)
    k_proj<<<dim3(BB * NN / 64, DD / 64), dim3(256), 0, stream>>>(Xbf, qwB, qbF, Qbf, nullptr, flag, 0, qscale);
    k_proj<<<dim3(BB * NN / 64, DD / 64), dim3(256), 0, stream>>>(Xbf, kwB, kbF, Kbf, nullptr, flag, 0, 1.0f);
    k_proj<<<dim3(BB * NN / 64, DD / 64), dim3(256), 0, stream>>>(Xbf, vwB, vbF, Vtb, nullptr, flag, 2, 1.0f);

    k_attn<<<dim3(NN / 64, HH, BB), dim3(256), 0, stream>>>(Qbf, Kbf, Vtb, edgebits, colbits, AOb);

    k_proj<<<dim3(BB * NN / 64, DD / 64), dim3(256), 0, stream>>>(AOb, owB, obF, nullptr, d_out, flag, 3, 1.0f);
}

// Round 5
// 574.307 us; speedup vs baseline: 1.7766x; 1.0381x over previous
//
#include <hip/hip_runtime.h>
#include <hip/hip_bf16.h>

// Problem constants (B,N,D,H,E from reference; hd = D/H)
#define BB   2
#define NN   2048
#define DD   256
#define HH   8
#define HD   32
#define EE   65536
#define KTOP 1024   // N * (1 - 0.5)
#define NT   13     // float tensors to canonicalize
#define NSPLIT 4    // attention column splits

typedef __attribute__((ext_vector_type(8))) short bf16x8;
typedef __attribute__((ext_vector_type(4))) float f32x4;

__device__ __forceinline__ float bf2f(unsigned short u) {
    return __uint_as_float(((unsigned)u) << 16);
}
__device__ __forceinline__ unsigned short f2bf(float f) {
    __hip_bfloat16 h = __float2bfloat16(f);
    return *reinterpret_cast<unsigned short*>(&h);
}

// ---------------------------------------------------------------------------
// Dtype detector: read first 64K ushorts of x as bf16. fp32 data misread as
// bf16 has random exponents in the odd halves -> max blows past 1e10.
// flag: 1 = fp32, 0 = bf16.
// ---------------------------------------------------------------------------
__global__ __launch_bounds__(256) void k_detect(const void* __restrict__ x, int* __restrict__ flag)
{
    __shared__ float red[256];
    const unsigned short* u = (const unsigned short*)x;
    float mx = 0.f;
    for (int i = threadIdx.x; i < 65536; i += 256) {
        float v = fabsf(bf2f(u[i]));
        if (!(v <= 1e10f)) v = 1e30f;       // NaN / inf / huge -> big
        mx = fmaxf(mx, v);
    }
    red[threadIdx.x] = mx;
    __syncthreads();
    for (int s = 128; s > 0; s >>= 1) {
        if (threadIdx.x < s) red[threadIdx.x] = fmaxf(red[threadIdx.x], red[threadIdx.x + s]);
        __syncthreads();
    }
    if (threadIdx.x == 0) *flag = (red[0] > 1e10f) ? 1 : 0;
}

// ---------------------------------------------------------------------------
// Canonicalize float tensors to fp32 (+ optional bf16 copy) in workspace.
// ---------------------------------------------------------------------------
struct ConvArgs {
    const void*     src[NT];
    float*          dst[NT];
    unsigned short* dstB[NT];   // nullable: also emit bf16
    int             n[NT];
};

__global__ __launch_bounds__(256) void k_convert(ConvArgs a, const int* __restrict__ flag)
{
    int t = blockIdx.y;
    int n = a.n[t];
    int fp = *flag;
    const float* sf = (const float*)a.src[t];
    const unsigned short* sb = (const unsigned short*)a.src[t];
    float* d = a.dst[t];
    unsigned short* db = a.dstB[t];
    for (int i = blockIdx.x * 256 + threadIdx.x; i < n; i += gridDim.x * 256) {
        float v = fp ? sf[i] : bf2f(sb[i]);
        d[i] = v;
        if (db) db[i] = f2bf(v);
    }
}

// ---------------------------------------------------------------------------
// topo[b,n] = g2 @ relu(g1 @ x[b,n] + g1_b) + g2_b      (hidden = 128)
// Kept pure fp32 (top-k rank stability). Tiled GEMM structure: coalesced
// weight staging (the old per-lane g1w row walk was 64 cache lines / wave).
// 16 rows/block, 256 blocks. Thread (rg=t>>7, c=t&127): 8 rows x hidden c.
// ---------------------------------------------------------------------------
__global__ __launch_bounds__(256) void k_topo(
    const float* __restrict__ x,
    const float* __restrict__ g1w, const float* __restrict__ g1b,
    const float* __restrict__ g2w, const float* __restrict__ g2b,
    float* __restrict__ topo)
{
    __shared__ float xs[16][DD];        // 16 KB
    __shared__ float wt[16][129];       // staged g1w K-slice
    __shared__ float red[16][132];      // relu(h)*g2w contributions
    int t = threadIdx.x;
    int c  = t & 127;                   // hidden unit
    int rg = t >> 7;                    // 0/1 -> rows rg*8..+8
    int row0 = blockIdx.x * 16;

    const float4* X4 = reinterpret_cast<const float4*>(x + (size_t)row0 * DD);
    for (int i = t; i < 16 * 64; i += 256) {
        int r = i >> 6, k4 = i & 63;
        *reinterpret_cast<float4*>(&xs[r][k4 * 4]) = X4[(size_t)r * 64 + k4];
    }
    float acc[8];
#pragma unroll
    for (int r = 0; r < 8; ++r) acc[r] = 0.f;

    for (int kt = 0; kt < DD; kt += 16) {
        __syncthreads();
        for (int i = t; i < 128 * 16; i += 256) {
            int nn = i >> 4, kk = i & 15;
            wt[kk][nn] = g1w[(size_t)nn * DD + kt + kk];
        }
        __syncthreads();
        float wv[16];
#pragma unroll
        for (int kk = 0; kk < 16; ++kk) wv[kk] = wt[kk][c];
#pragma unroll
        for (int r = 0; r < 8; ++r) {
            const float* xr = &xs[rg * 8 + r][kt];
            float4 x0 = *reinterpret_cast<const float4*>(xr);
            float4 x1 = *reinterpret_cast<const float4*>(xr + 4);
            float4 x2 = *reinterpret_cast<const float4*>(xr + 8);
            float4 x3 = *reinterpret_cast<const float4*>(xr + 12);
            acc[r] += x0.x*wv[0] + x0.y*wv[1] + x0.z*wv[2] + x0.w*wv[3]
                    + x1.x*wv[4] + x1.y*wv[5] + x1.z*wv[6] + x1.w*wv[7]
                    + x2.x*wv[8] + x2.y*wv[9] + x2.z*wv[10] + x2.w*wv[11]
                    + x3.x*wv[12] + x3.y*wv[13] + x3.z*wv[14] + x3.w*wv[15];
        }
    }
    float gb = g1b[c], gw = g2w[c];
#pragma unroll
    for (int r = 0; r < 8; ++r)
        red[rg * 8 + r][c] = fmaxf(acc[r] + gb, 0.f) * gw;
    __syncthreads();
    int rr = t >> 4, ii = t & 15;       // 16 rows x 16 lanes
    float p = 0.f;
#pragma unroll
    for (int j = 0; j < 8; ++j) p += red[rr][ii * 8 + j];
#pragma unroll
    for (int o = 1; o < 16; o <<= 1) p += __shfl_xor(p, o, 64);
    if (ii == 0) topo[row0 + rr] = p + g2b[0];
}

// ---------------------------------------------------------------------------
// Stable top-k -> column bit mask (jax.lax.top_k stable-tie semantics).
// ---------------------------------------------------------------------------
__global__ __launch_bounds__(256) void k_rank(
    const float* __restrict__ topo, unsigned* __restrict__ colbits)
{
    int b = blockIdx.y;
    int m = blockIdx.x * 256 + threadIdx.x;
    __shared__ float tl[NN];
    for (int i = threadIdx.x; i < NN; i += 256) tl[i] = topo[b * NN + i];
    __syncthreads();
    float v = tl[m];
    int rank = 0;
    for (int j = 0; j < NN; ++j) {
        float vj = tl[j];
        rank += (vj > v) || (vj == v && j < m);
    }
    if (rank < KTOP) atomicOr(&colbits[b * 64 + (m >> 5)], 1u << (m & 31));
}

// ---------------------------------------------------------------------------
// Edge bitmask: edgebits[n][m/32] |= bit(m)
// ---------------------------------------------------------------------------
__global__ __launch_bounds__(256) void k_edges(
    const int* __restrict__ ei, unsigned* __restrict__ edgebits)
{
    int e = blockIdx.x * 256 + threadIdx.x;
    if (e >= EE) return;
    int r = ei[e];
    int c = ei[EE + e];
    atomicOr(&edgebits[r * 64 + (c >> 5)], 1u << (c & 31));
}

// ---------------------------------------------------------------------------
// sparse_mask output [B,H,N,N]: value = edge|col bit. Store dtype per flag.
// ---------------------------------------------------------------------------
__global__ __launch_bounds__(256) void k_maskout(
    const unsigned* __restrict__ edgebits, const unsigned* __restrict__ colbits,
    void* __restrict__ dout, const int* __restrict__ flag)
{
    int row = blockIdx.x;                 // b*N + n
    int b = row / NN, n = row % NN;
    int t = threadIdx.x;                  // covers cols t*8 .. t*8+7
    unsigned w = edgebits[n * 64 + (t >> 2)] | colbits[b * 64 + (t >> 2)];
    unsigned bits = (w >> ((t & 3) * 8)) & 0xFFu;
    if (*flag) {
        float v[8];
#pragma unroll
        for (int i = 0; i < 8; ++i) v[i] = ((bits >> i) & 1) ? 1.f : 0.f;
        float* base = (float*)dout + (size_t)BB * NN * DD;
#pragma unroll
        for (int h = 0; h < HH; ++h) {
            size_t idx = ((((size_t)(b * HH + h)) * NN + n) * NN) + (size_t)t * 8;
            *reinterpret_cast<float4*>(base + idx)     = make_float4(v[0], v[1], v[2], v[3]);
            *reinterpret_cast<float4*>(base + idx + 4) = make_float4(v[4], v[5], v[6], v[7]);
        }
    } else {
        unsigned v[8];
#pragma unroll
        for (int i = 0; i < 8; ++i) v[i] = ((bits >> i) & 1) ? 0x3F80u : 0u;
        uint4 o4;
        o4.x = v[0] | (v[1] << 16);
        o4.y = v[2] | (v[3] << 16);
        o4.z = v[4] | (v[5] << 16);
        o4.w = v[6] | (v[7] << 16);
        unsigned short* base = (unsigned short*)dout + (size_t)BB * NN * DD;
#pragma unroll
        for (int h = 0; h < HH; ++h) {
            size_t idx = ((((size_t)(b * HH + h)) * NN + n) * NN) + (size_t)t * 8;
            *reinterpret_cast<uint4*>(base + idx) = o4;
        }
    }
}

// ---------------------------------------------------------------------------
// MFMA projection GEMM: C[row,col] = X[row,:].W[col,:] + bias[col], K=256.
// mode 0: bf16 head layout [b][h][n][j], *(scale)  (Q, K)
// mode 2: bf16 transposed head layout [b][h][j][n] (V -> Vt)
// mode 3: store to d_out (dtype per flag), row-major
// ---------------------------------------------------------------------------
__global__ __launch_bounds__(256) void k_proj(
    const unsigned short* __restrict__ Xb, const unsigned short* __restrict__ Wb,
    const float* __restrict__ bias, unsigned short* __restrict__ outB,
    void* __restrict__ dout, const int* __restrict__ flag, int mode, float scale)
{
    int t = threadIdx.x;
    int w = t >> 6, lane = t & 63, q4 = lane >> 4, l16 = lane & 15;
    int m0 = blockIdx.x * 64 + w * 16;
    int nb = blockIdx.y * 64;

    f32x4 acc[4] = {{0.f,0.f,0.f,0.f},{0.f,0.f,0.f,0.f},{0.f,0.f,0.f,0.f},{0.f,0.f,0.f,0.f}};
#pragma unroll
    for (int ks = 0; ks < 8; ++ks) {
        bf16x8 a = *reinterpret_cast<const bf16x8*>(Xb + (size_t)(m0 + l16) * DD + ks * 32 + q4 * 8);
#pragma unroll
        for (int n = 0; n < 4; ++n) {
            bf16x8 bf = *reinterpret_cast<const bf16x8*>(Wb + (size_t)(nb + n * 16 + l16) * DD + ks * 32 + q4 * 8);
            acc[n] = __builtin_amdgcn_mfma_f32_16x16x32_bf16(a, bf, acc[n], 0, 0, 0);
        }
    }

#pragma unroll
    for (int n = 0; n < 4; ++n) {
        int col = nb + n * 16 + l16;
        float bv = bias[col];
#pragma unroll
        for (int i = 0; i < 4; ++i) {
            int row = m0 + q4 * 4 + i;
            float v = (acc[n][i] + bv) * scale;
            if (mode == 0) {
                int b = row >> 11, n2 = row & (NN - 1);
                int h = col >> 5,  j  = col & (HD - 1);
                outB[(((size_t)(b * HH + h)) * NN + n2) * HD + j] = f2bf(v);
            } else if (mode == 2) {
                int b = row >> 11, n2 = row & (NN - 1);
                int h = col >> 5,  j  = col & (HD - 1);
                outB[(((size_t)(b * HH + h)) * HD + j) * NN + n2] = f2bf(v);
            } else {
                if (*flag) ((float*)dout)[(size_t)row * DD + col] = v;
                else ((unsigned short*)dout)[(size_t)row * DD + col] = f2bf(v);
            }
        }
    }
}

// ---------------------------------------------------------------------------
// Fused masked attention, MFMA, split-K over columns (NSPLIT partials).
// No max-shift, so partials are purely additive: each split writes
// Opart (fp32), Zpart, Spart; k_comb sums and normalizes.
// Grid: (32*NSPLIT, H, B); block = 4 waves, 64 Q rows; 16 chunks of 32 cols.
// ---------------------------------------------------------------------------
__global__ __launch_bounds__(256) void k_attn(
    const unsigned short* __restrict__ Qbf, const unsigned short* __restrict__ Kbf,
    const unsigned short* __restrict__ Vt,
    const unsigned* __restrict__ edgebits, const unsigned* __restrict__ colbits,
    float* __restrict__ Opart, float* __restrict__ Zpart, float* __restrict__ Spart)
{
    int blk   = blockIdx.x;
    int split = blk & (NSPLIT - 1);
    int rt    = blk >> 2;           // 64-row tile 0..31
    int h  = blockIdx.y;
    int b  = blockIdx.z;
    int t  = threadIdx.x;
    int w    = t >> 6;              // wave 0..3
    int lane = t & 63;
    int q4   = lane >> 4;           // quad 0..3
    int l16  = lane & 15;

    __shared__ unsigned mw[64][17];            // this split's mask words
    __shared__ short Pl[4][2][16 * 40];        // [wave][buf][row*40 + col]

    const int r0 = rt * 64;
    const int c0 = split * 16;                 // first chunk index
    for (int i = t; i < 64 * 16; i += 256) {
        int r = i >> 4, wd = i & 15;
        mw[r][wd] = edgebits[(r0 + r) * 64 + c0 + wd] | colbits[b * 64 + c0 + wd];
    }
    __syncthreads();

    const unsigned short* Qp = Qbf + ((size_t)(b * HH + h)) * NN * HD;
    const unsigned short* Kp = Kbf + ((size_t)(b * HH + h)) * NN * HD;
    const unsigned short* Vp = Vt  + ((size_t)(b * HH + h)) * HD * NN;

    bf16x8 afrag = *reinterpret_cast<const bf16x8*>(Qp + (size_t)(r0 + w * 16 + l16) * HD + q4 * 8);

    f32x4 O0 = {0.f, 0.f, 0.f, 0.f}, O1 = {0.f, 0.f, 0.f, 0.f};
    float Zp[4] = {0.f, 0.f, 0.f, 0.f}, Sp[4] = {0.f, 0.f, 0.f, 0.f};

    for (int chl = 0; chl < 16; ++chl) {
        int n0 = (c0 + chl) * 32;
        bf16x8 kb0 = *reinterpret_cast<const bf16x8*>(Kp + (size_t)(n0 + l16) * HD + q4 * 8);
        bf16x8 kb1 = *reinterpret_cast<const bf16x8*>(Kp + (size_t)(n0 + 16 + l16) * HD + q4 * 8);
        f32x4 s0 = __builtin_amdgcn_mfma_f32_16x16x32_bf16(afrag, kb0, (f32x4){0.f,0.f,0.f,0.f}, 0, 0, 0);
        f32x4 s1 = __builtin_amdgcn_mfma_f32_16x16x32_bf16(afrag, kb1, (f32x4){0.f,0.f,0.f,0.f}, 0, 0, 0);

        short* P = &Pl[w][chl & 1][0];
#pragma unroll
        for (int i = 0; i < 4; ++i) {
            int rl = w * 16 + q4 * 4 + i;          // block-local row
            unsigned wdv = mw[rl][chl];
            float e0 = __expf(s0[i]);
            float e1 = __expf(s1[i]);
            float m0 = ((wdv >> l16) & 1u) ? e0 : 0.f;
            float m1 = ((wdv >> (16 + l16)) & 1u) ? e1 : 0.f;
            Zp[i] += e0 + e1;
            Sp[i] += m0 + m1;
            int prow = q4 * 4 + i;
            P[prow * 40 + l16]      = (short)f2bf(m0);
            P[prow * 40 + 16 + l16] = (short)f2bf(m1);
        }
        asm volatile("s_waitcnt lgkmcnt(0)" ::: "memory");
        bf16x8 pfrag = *reinterpret_cast<const bf16x8*>(P + l16 * 40 + q4 * 8);
        bf16x8 vb0 = *reinterpret_cast<const bf16x8*>(Vp + (size_t)l16 * NN + n0 + q4 * 8);
        bf16x8 vb1 = *reinterpret_cast<const bf16x8*>(Vp + (size_t)(16 + l16) * NN + n0 + q4 * 8);
        O0 = __builtin_amdgcn_mfma_f32_16x16x32_bf16(pfrag, vb0, O0, 0, 0, 0);
        O1 = __builtin_amdgcn_mfma_f32_16x16x32_bf16(pfrag, vb1, O1, 0, 0, 0);
    }

#pragma unroll
    for (int o = 1; o < 16; o <<= 1) {
#pragma unroll
        for (int i = 0; i < 4; ++i) {
            Zp[i] += __shfl_xor(Zp[i], o, 64);
            Sp[i] += __shfl_xor(Sp[i], o, 64);
        }
    }
#pragma unroll
    for (int i = 0; i < 4; ++i) {
        int n = r0 + w * 16 + q4 * 4 + i;
        float* op = Opart + (size_t)split * BB * NN * DD + ((size_t)(b * NN + n)) * DD + h * HD;
        op[l16]      = O0[i];
        op[16 + l16] = O1[i];
        if (l16 == 0) {
            size_t zi = (((size_t)(split * BB + b)) * HH + h) * NN + n;
            Zpart[zi] = Zp[i];
            Spart[zi] = Sp[i];
        }
    }
}

// ---------------------------------------------------------------------------
// Combine split-K partials, normalize, emit bf16 AO. One block per (b,n).
// ---------------------------------------------------------------------------
__global__ __launch_bounds__(256) void k_comb(
    const float* __restrict__ Opart, const float* __restrict__ Zpart,
    const float* __restrict__ Spart, unsigned short* __restrict__ AOb)
{
    int row = blockIdx.x;       // b*N + n
    int t = threadIdx.x;        // d in 0..255
    int b = row >> 11, n = row & (NN - 1);
    int h = t >> 5;
    float Z = 0.f, S = 0.f, O = 0.f;
#pragma unroll
    for (int s = 0; s < NSPLIT; ++s) {
        size_t zi = (((size_t)(s * BB + b)) * HH + h) * NN + n;
        Z += Zpart[zi];
        S += Spart[zi];
        O += Opart[(size_t)s * BB * NN * DD + (size_t)row * DD + t];
    }
    AOb[(size_t)row * DD + t] = f2bf(O / (S + 1e-8f * Z));
}

// ---------------------------------------------------------------------------
extern "C" void kernel_launch(void* const* d_in, const int* in_sizes, int n_in,
                              void* d_out, int out_size, void* d_ws, size_t ws_size,
                              hipStream_t stream)
{
    const void* x   = d_in[0];
    const int*  ei  = (const int*)d_in[1];

    // workspace layout (bytes)
    char* ws = (char*)d_ws;
    constexpr size_t OFF_FLAG = 0;
    constexpr size_t OFF_EB   = 256;
    constexpr size_t OFF_CB   = OFF_EB  + (size_t)NN * 64 * 4;
    constexpr size_t OFF_TOPO = OFF_CB  + (size_t)BB * 64 * 4;
    constexpr size_t OFF_XF   = OFF_TOPO + (size_t)BB * NN * 4;
    constexpr size_t OFF_QW   = OFF_XF  + (size_t)BB * NN * DD * 4;
    constexpr size_t OFF_KW   = OFF_QW  + (size_t)DD * DD * 4;
    constexpr size_t OFF_VW   = OFF_KW  + (size_t)DD * DD * 4;
    constexpr size_t OFF_OW   = OFF_VW  + (size_t)DD * DD * 4;
    constexpr size_t OFF_QB   = OFF_OW  + (size_t)DD * DD * 4;
    constexpr size_t OFF_KB   = OFF_QB  + (size_t)DD * 4;
    constexpr size_t OFF_VB   = OFF_KB  + (size_t)DD * 4;
    constexpr size_t OFF_OB   = OFF_VB  + (size_t)DD * 4;
    constexpr size_t OFF_G1W  = OFF_OB  + (size_t)DD * 4;
    constexpr size_t OFF_G1B  = OFF_G1W + (size_t)(DD / 2) * DD * 4;
    constexpr size_t OFF_G2W  = OFF_G1B + (size_t)(DD / 2) * 4;
    constexpr size_t OFF_G2B  = OFF_G2W + (size_t)(DD / 2) * 4;
    constexpr size_t OFF_Q    = OFF_G2B + 256;                        // bf16 head layout
    constexpr size_t OFF_K    = OFF_Q   + (size_t)BB * NN * DD * 2;
    constexpr size_t OFF_VT   = OFF_K   + (size_t)BB * NN * DD * 2;   // bf16 transposed
    constexpr size_t OFF_AOB  = OFF_VT  + (size_t)BB * NN * DD * 2;   // bf16 attn out
    constexpr size_t OFF_XB   = OFF_AOB + (size_t)BB * NN * DD * 2;   // bf16 x
    constexpr size_t OFF_QWB  = OFF_XB  + (size_t)BB * NN * DD * 2;   // bf16 weights
    constexpr size_t OFF_KWB  = OFF_QWB + (size_t)DD * DD * 2;
    constexpr size_t OFF_VWB  = OFF_KWB + (size_t)DD * DD * 2;
    constexpr size_t OFF_OWB  = OFF_VWB + (size_t)DD * DD * 2;
    constexpr size_t OFF_OP   = OFF_OWB + (size_t)DD * DD * 2;        // split-K partials
    constexpr size_t OFF_ZP   = OFF_OP  + (size_t)NSPLIT * BB * NN * DD * 4;
    constexpr size_t OFF_SP   = OFF_ZP  + (size_t)NSPLIT * BB * HH * NN * 4;

    int*      flag     = (int*)(ws + OFF_FLAG);
    unsigned* edgebits = (unsigned*)(ws + OFF_EB);
    unsigned* colbits  = (unsigned*)(ws + OFF_CB);
    float*    topo     = (float*)(ws + OFF_TOPO);
    float*    xF       = (float*)(ws + OFF_XF);
    float*    qwF      = (float*)(ws + OFF_QW);
    float*    kwF      = (float*)(ws + OFF_KW);
    float*    vwF      = (float*)(ws + OFF_VW);
    float*    owF      = (float*)(ws + OFF_OW);
    float*    qbF      = (float*)(ws + OFF_QB);
    float*    kbF      = (float*)(ws + OFF_KB);
    float*    vbF      = (float*)(ws + OFF_VB);
    float*    obF      = (float*)(ws + OFF_OB);
    float*    g1wF     = (float*)(ws + OFF_G1W);
    float*    g1bF     = (float*)(ws + OFF_G1B);
    float*    g2wF     = (float*)(ws + OFF_G2W);
    float*    g2bF     = (float*)(ws + OFF_G2B);
    unsigned short* Qbf = (unsigned short*)(ws + OFF_Q);
    unsigned short* Kbf = (unsigned short*)(ws + OFF_K);
    unsigned short* Vtb = (unsigned short*)(ws + OFF_VT);
    unsigned short* AOb = (unsigned short*)(ws + OFF_AOB);
    unsigned short* Xbf = (unsigned short*)(ws + OFF_XB);
    unsigned short* qwB = (unsigned short*)(ws + OFF_QWB);
    unsigned short* kwB = (unsigned short*)(ws + OFF_KWB);
    unsigned short* vwB = (unsigned short*)(ws + OFF_VWB);
    unsigned short* owB = (unsigned short*)(ws + OFF_OWB);
    float*    Opart    = (float*)(ws + OFF_OP);
    float*    Zpart    = (float*)(ws + OFF_ZP);
    float*    Spart    = (float*)(ws + OFF_SP);

    // zero flag + edge/col bitmasks
    hipMemsetAsync(d_ws, 0, OFF_TOPO, stream);

    k_detect<<<dim3(1), dim3(256), 0, stream>>>(x, flag);

    ConvArgs ca;
    const int din_idx[NT] = {0, 2, 4, 6, 8, 3, 5, 7, 9, 10, 11, 12, 13};
    float* dsts[NT] = {xF, qwF, kwF, vwF, owF, qbF, kbF, vbF, obF, g1wF, g1bF, g2wF, g2bF};
    unsigned short* dstsB[NT] = {Xbf, qwB, kwB, vwB, owB,
                                 nullptr, nullptr, nullptr, nullptr,
                                 nullptr, nullptr, nullptr, nullptr};
    for (int i = 0; i < NT; ++i) {
        ca.src[i]  = d_in[din_idx[i]];
        ca.dst[i]  = dsts[i];
        ca.dstB[i] = dstsB[i];
        ca.n[i]    = in_sizes[din_idx[i]];
    }
    k_convert<<<dim3(64, NT), dim3(256), 0, stream>>>(ca, flag);

    k_topo<<<dim3(BB * NN / 16), dim3(256), 0, stream>>>(xF, g1wF, g1bF, g2wF, g2bF, topo);
    k_rank<<<dim3(NN / 256, BB), dim3(256), 0, stream>>>(topo, colbits);
    k_edges<<<dim3(EE / 256), dim3(256), 0, stream>>>(ei, edgebits);
    k_maskout<<<dim3(BB * NN), dim3(256), 0, stream>>>(edgebits, colbits, d_out, flag);

    const float qscale = 0.17677669529663687f;   // 1/sqrt(32)
    k_proj<<<dim3(BB * NN / 64, DD / 64), dim3(256), 0, stream>>>(Xbf, qwB, qbF, Qbf, nullptr, flag, 0, qscale);
    k_proj<<<dim3(BB * NN / 64, DD / 64), dim3(256), 0, stream>>>(Xbf, kwB, kbF, Kbf, nullptr, flag, 0, 1.0f);
    k_proj<<<dim3(BB * NN / 64, DD / 64), dim3(256), 0, stream>>>(Xbf, vwB, vbF, Vtb, nullptr, flag, 2, 1.0f);

    k_attn<<<dim3((NN / 64) * NSPLIT, HH, BB), dim3(256), 0, stream>>>(
        Qbf, Kbf, Vtb, edgebits, colbits, Opart, Zpart, Spart);
    k_comb<<<dim3(BB * NN), dim3(256), 0, stream>>>(Opart, Zpart, Spart, AOb);

    k_proj<<<dim3(BB * NN / 64, DD / 64), dim3(256), 0, stream>>>(AOb, owB, obF, nullptr, d_out, flag, 3, 1.0f);
}